// Round 15
// baseline (178.750 us; speedup 1.0000x reference)
//
#include <hip/hip_runtime.h>

#define NN 100000
#define NE 1000000
#define IND 128
#define OUTD 64
#define GM 64                     // gemm node tile
#define MAXDEG 64                 // fixed-stride CSR row capacity
#define GEMM_BLKS ((NN + GM - 1) / GM)      // 1563
#define BUCK_BLKS ((NE + 255) / 256)        // 3907
#define FUSE_GRPS 782                       // 2 gemm + 5 bucket per group

typedef float vf4 __attribute__((ext_vector_type(4)));
typedef short bf8 __attribute__((ext_vector_type(8)));  // 8 bf16 = MFMA A/B frag
typedef unsigned int u32;

__device__ __forceinline__ unsigned short f2bf(float f) {  // RNE
    unsigned int x = __float_as_uint(f);
    return (unsigned short)((x + 0x7fffu + ((x >> 16) & 1u)) >> 16);
}
__device__ __forceinline__ unsigned int packbf(float a, float b) {
    return (unsigned int)f2bf(a) | ((unsigned int)f2bf(b) << 16);
}
__device__ __forceinline__ float lo16(unsigned int u) { return __uint_as_float(u << 16); }
__device__ __forceinline__ float hi16(unsigned int u) { return __uint_as_float(u & 0xffff0000u); }

// ---------------- FUSED: {count+bucket} (5/7 blocks) || gemm_raw (2/7) ----
// bucket: ONE atomic pass builds fixed-stride CSR (rank = atomic return).
// gemm_raw: MFMA gemm -> h016 = bf16(h0) unscaled. No norms needed anywhere
// downstream: gathers derive r from cnt on the fly.

__global__ __launch_bounds__(256) void k_build_gemm(
        const float* __restrict__ feat, const float* __restrict__ W,
        const float* __restrict__ bias,
        unsigned short* __restrict__ h016,
        const int* __restrict__ src, const int* __restrict__ dst,
        int* __restrict__ cnt, int* __restrict__ colidx) {
    int g = blockIdx.x / 7, m = blockIdx.x % 7;
    if (m >= 2) {                     // ---- count+bucket part ----
        int b = g * 5 + (m - 2);
        if (b < BUCK_BLKS) {
            int e = b * 256 + threadIdx.x;
            if (e < NE) {
                int d = dst[e];
                int rank = atomicAdd(&cnt[d], 1);
                if (rank < MAXDEG) colidx[d * MAXDEG + rank] = src[e];
            }
        }
        return;
    }
    int gb = g * 2 + m;               // ---- gemm part ----
    if (gb >= GEMM_BLKS) return;

    __shared__ u32 Fl[GM * 64];    // 16 KB swizzled bf16
    __shared__ u32 Wl[OUTD * 64];  // 16 KB
    int t = threadIdx.x;
    int n0 = gb * GM;

#pragma unroll
    for (int i = 0; i < 4; ++i) {
        int c = t + i * 256;
        int row = c >> 4, kc8 = c & 15;
        vf4 x0 = ((const vf4*)W)[row * 32 + kc8 * 2];
        vf4 x1 = ((const vf4*)W)[row * 32 + kc8 * 2 + 1];
        uint4 p;
        p.x = packbf(x0.x, x0.y); p.y = packbf(x0.z, x0.w);
        p.z = packbf(x1.x, x1.y); p.w = packbf(x1.z, x1.w);
        *(uint4*)((char*)Wl + row * 256 + ((kc8 ^ (row & 7)) << 4)) = p;
    }
#pragma unroll
    for (int i = 0; i < 4; ++i) {
        int c = t + i * 256;
        int row = c >> 4, kc8 = c & 15;
        int n = n0 + row;
        vf4 x0 = (vf4)(0.0f), x1 = (vf4)(0.0f);
        if (n < NN) {
            x0 = __builtin_nontemporal_load(&((const vf4*)feat)[n * 32 + kc8 * 2]);
            x1 = __builtin_nontemporal_load(&((const vf4*)feat)[n * 32 + kc8 * 2 + 1]);
        }
        uint4 p;
        p.x = packbf(x0.x, x0.y); p.y = packbf(x0.z, x0.w);
        p.z = packbf(x1.x, x1.y); p.w = packbf(x1.z, x1.w);
        *(uint4*)((char*)Fl + row * 256 + ((kc8 ^ (row & 7)) << 4)) = p;
    }
    __syncthreads();

    int lane = t & 63, wv = t >> 6;
    int mrow = lane & 15, q = lane >> 4;
    vf4 acc[4];
#pragma unroll
    for (int ct = 0; ct < 4; ++ct) acc[ct] = (vf4)(0.0f);

    int arow = wv * 16 + mrow;
#pragma unroll
    for (int kc = 0; kc < 4; ++kc) {
        bf8 a = *(const bf8*)((const char*)Fl + arow * 256 +
                              (((kc * 4 + q) ^ (arow & 7)) << 4));
#pragma unroll
        for (int ct = 0; ct < 4; ++ct) {
            int ch = ct * 16 + mrow;
            bf8 b = *(const bf8*)((const char*)Wl + ch * 256 +
                                  (((kc * 4 + q) ^ (ch & 7)) << 4));
            acc[ct] = __builtin_amdgcn_mfma_f32_16x16x32_bf16(a, b, acc[ct], 0, 0, 0);
        }
    }

    float bv[4];
#pragma unroll
    for (int ct = 0; ct < 4; ++ct) bv[ct] = bias[ct * 16 + mrow];

#pragma unroll
    for (int reg = 0; reg < 4; ++reg) {
        int n = n0 + wv * 16 + q * 4 + reg;
        if (n < NN) {
#pragma unroll
            for (int ct = 0; ct < 4; ++ct) {
                int ch = ct * 16 + mrow;
                h016[(size_t)n * OUTD + ch] = f2bf(acc[ct][reg] + bv[ct]);
            }
        }
    }
}

// ---------------- propagation: unscaled-state batch-8 gather ----------------
// Wave = 8 nodes x 8 channel-groups; lane owns 8 channels of one node.
// State h16 = bf16(h), unscaled. r derived from cnt on the fly (cnt is
// L2-resident; 8 lanes broadcast-load cnt[s]; rsqrt is ~free VALU).
// out = 0.5*r_v*sum(r_s*h_s) + 0.5*h_v + 0.5*h0_v*r_v^2

template<bool FIRST, bool FINAL>
__global__ __launch_bounds__(256) void k_gather16(
        float* __restrict__ hn, unsigned short* __restrict__ gn16,
        const unsigned short* __restrict__ st16,
        const unsigned short* __restrict__ h016,
        const int* __restrict__ cnt, const int* __restrict__ colidx) {
    int t = blockIdx.x * 256 + threadIdx.x;
    int wave = t >> 6;
    int lane = t & 63;
    int q  = lane >> 3;    // node slot
    int c8 = lane & 7;     // channel group
    int v = wave * 8 + q;
    bool valid = v < NN;
    int vc = valid ? v : NN - 1;
    int dc = cnt[vc];                    // true degree (for r)
    float rv = rsqrtf((float)dc + 1.0f);
    int deg = min(dc, MAXDEG);
    if (!valid) deg = 0;
    int beg = vc * MAXDEG;
    int md = deg;
    md = max(md, __shfl_xor(md, 8, 64));
    md = max(md, __shfl_xor(md, 16, 64));
    md = max(md, __shfl_xor(md, 32, 64));

    float a0 = 0.f, a1 = 0.f, a2 = 0.f, a3 = 0.f;
    float a4 = 0.f, a5 = 0.f, a6 = 0.f, a7 = 0.f;
    int nb = (md + 7) >> 3;
    for (int b = 0; b < nb; ++b) {
        int kb = b * 8;
        int sj[8]; int cj[8]; uint4 u[8];
#pragma unroll
        for (int j = 0; j < 8; ++j) {
            int k = kb + j;
            sj[j] = (k < deg) ? colidx[beg + k] : 0;   // clamped -> valid addr
        }
#pragma unroll
        for (int j = 0; j < 8; ++j) {
            u[j]  = *(const uint4*)(st16 + (size_t)sj[j] * OUTD + 8 * c8);
            cj[j] = cnt[sj[j]];                        // L2-hot, same-addr x8 lanes
        }
#pragma unroll
        for (int j = 0; j < 8; ++j) {
            if (kb + j < deg) {
                float rs = rsqrtf((float)cj[j] + 1.0f);
                a0 = fmaf(rs, lo16(u[j].x), a0); a1 = fmaf(rs, hi16(u[j].x), a1);
                a2 = fmaf(rs, lo16(u[j].y), a2); a3 = fmaf(rs, hi16(u[j].y), a3);
                a4 = fmaf(rs, lo16(u[j].z), a4); a5 = fmaf(rs, hi16(u[j].z), a5);
                a6 = fmaf(rs, lo16(u[j].w), a6); a7 = fmaf(rs, hi16(u[j].w), a7);
            }
        }
    }

    if (valid) {
        float hr  = 0.5f * rv;
        float s2h = 0.5f * rv * rv;      // hinit factor: 0.5*r^2 applied to h0
        size_t base = (size_t)v * OUTD + 8 * c8;
        uint4 us = *(const uint4*)(st16 + base);
        uint4 u0 = FIRST ? us : *(const uint4*)(h016 + base);
        float o0 = fmaf(hr, a0, fmaf(s2h, lo16(u0.x), 0.5f * lo16(us.x)));
        float o1 = fmaf(hr, a1, fmaf(s2h, hi16(u0.x), 0.5f * hi16(us.x)));
        float o2 = fmaf(hr, a2, fmaf(s2h, lo16(u0.y), 0.5f * lo16(us.y)));
        float o3 = fmaf(hr, a3, fmaf(s2h, hi16(u0.y), 0.5f * hi16(us.y)));
        float o4 = fmaf(hr, a4, fmaf(s2h, lo16(u0.z), 0.5f * lo16(us.z)));
        float o5 = fmaf(hr, a5, fmaf(s2h, hi16(u0.z), 0.5f * hi16(us.z)));
        float o6 = fmaf(hr, a6, fmaf(s2h, lo16(u0.w), 0.5f * lo16(us.w)));
        float o7 = fmaf(hr, a7, fmaf(s2h, hi16(u0.w), 0.5f * hi16(us.w)));
        if (FINAL) {
            vf4 w0 = { o0, o1, o2, o3 };
            vf4 w1 = { o4, o5, o6, o7 };
            __builtin_nontemporal_store(w0, (vf4*)(hn + base));
            __builtin_nontemporal_store(w1, (vf4*)(hn + base + 4));
        } else {
            uint4 p;
            p.x = packbf(o0, o1);
            p.y = packbf(o2, o3);
            p.z = packbf(o4, o5);
            p.w = packbf(o6, o7);
            *(uint4*)(gn16 + base) = p;
        }
    }
}

// ---------------- launch ----------------
// ws layout (bytes): cnt 400,000 | colidx 25,600,000 |
// h016 12,800,000 | hA 12,800,000 | hB 12,800,000  = 64.4 MB
// (ws_size >= 82,004,224 verified empirically in R7-R13 runs.)

extern "C" void kernel_launch(void* const* d_in, const int* in_sizes, int n_in,
                              void* d_out, int out_size, void* d_ws, size_t ws_size,
                              hipStream_t stream) {
    const float* feat = (const float*)d_in[0];
    const float* W    = (const float*)d_in[1];
    const float* bias = (const float*)d_in[2];
    const int*   src  = (const int*)d_in[3];
    const int*   dst  = (const int*)d_in[4];

    char* ws = (char*)d_ws;
    int*            cnt    = (int*)(ws + 0);
    int*            colidx = (int*)(ws + 400000);
    unsigned short* h016   = (unsigned short*)(ws + 26000000);
    unsigned short* hA     = (unsigned short*)(ws + 38800000);
    unsigned short* hB     = (unsigned short*)(ws + 51600000);

    hipMemsetAsync(cnt, 0, NN * sizeof(int), stream);

    k_build_gemm<<<FUSE_GRPS * 7, 256, 0, stream>>>(
        feat, W, bias, h016, src, dst, cnt, colidx);

    int gth_blocks = (NN + 31) / 32;    // 3125
    k_gather16<true,  false><<<gth_blocks, 256, 0, stream>>>(
        nullptr, hA, h016, h016, cnt, colidx);
    k_gather16<false, false><<<gth_blocks, 256, 0, stream>>>(
        nullptr, hB, hA, h016, cnt, colidx);
    k_gather16<false, false><<<gth_blocks, 256, 0, stream>>>(
        nullptr, hA, hB, h016, cnt, colidx);
    k_gather16<false, true><<<gth_blocks, 256, 0, stream>>>(
        (float*)d_out, nullptr, hA, h016, cnt, colidx);
}